// Round 6
// baseline (225.047 us; speedup 1.0000x reference)
//
#include <hip/hip_runtime.h>
#include <hip/hip_bf16.h>
#include <stdint.h>

#define D_MODEL 1024
#define NHEADS  16
#define DK      64
#define SEQ     2048
#define BATCH   2

typedef __bf16 bf16x8 __attribute__((ext_vector_type(8)));
typedef __bf16 bf16x4 __attribute__((ext_vector_type(4)));
typedef float  f32x4  __attribute__((ext_vector_type(4)));

__device__ __forceinline__ void async_copy16(const void* g, void* l) {
  __builtin_amdgcn_global_load_lds(
      (__attribute__((address_space(1))) void*)g,
      (__attribute__((address_space(3))) void*)l, 16, 0, 0);
}

// ---------------- weight casts only (qkv now read f32 by proj GEMM) ----------------
__global__ void cast_w(const float* __restrict__ wq, const float* __restrict__ wk,
                       const float* __restrict__ wv, const float* __restrict__ wo,
                       __bf16* __restrict__ owq, __bf16* __restrict__ owk,
                       __bf16* __restrict__ owv, __bf16* __restrict__ owo) {
  const float* in = blockIdx.y == 0 ? wq : blockIdx.y == 1 ? wk : blockIdx.y == 2 ? wv : wo;
  __bf16* out     = blockIdx.y == 0 ? owq : blockIdx.y == 1 ? owk : blockIdx.y == 2 ? owv : owo;
  size_t i = (size_t)(blockIdx.x * 256 + threadIdx.x) * 4;
  float4 val = *(const float4*)(in + i);
  bf16x4 o;
  o.x = (__bf16)val.x; o.y = (__bf16)val.y; o.z = (__bf16)val.z; o.w = (__bf16)val.w;
  *(bf16x4*)(out + i) = o;
}

// ---------------- proj GEMM: C[M,N] = A_f32[M,K] @ B_bf16[N,K]^T ----------------
// A staged in f32 via global_load_lds with XOR chunk swizzle:
//   chunk cc of row stored at LDS pos (cc ^ (row&7)) -> staging stays
//   wave-contiguous (global side is a gather), reads spread across banks.
__global__ __launch_bounds__(256, 2)
void gemm_af32_bt(const float* __restrict__ A0, const float* __restrict__ A1, const float* __restrict__ A2,
                  const __bf16* __restrict__ B0, const __bf16* __restrict__ B1, const __bf16* __restrict__ B2,
                  __bf16* __restrict__ C0, __bf16* __restrict__ C1, __bf16* __restrict__ C2,
                  int M, int N, int K) {
  const float* A; const __bf16* Bm; __bf16* C;
  if (blockIdx.z == 0)      { A = A0; Bm = B0; C = C0; }
  else if (blockIdx.z == 1) { A = A1; Bm = B1; C = C1; }
  else                      { A = A2; Bm = B2; C = C2; }

  __shared__ float  Ashf[128 * 32];
  __shared__ __bf16 Bsh[128 * 32];

  const int tid  = threadIdx.x;
  const int lane = tid & 63;
  const int w    = tid >> 6;
  const int quad = lane >> 4;
  const int l16  = lane & 15;
  const int wr   = w >> 1, wc = w & 1;
  const size_t m0 = (size_t)blockIdx.x * 128;
  const size_t n0 = (size_t)blockIdx.y * 128;

  f32x4 acc[4][4] = {};

  for (int k0 = 0; k0 < K; k0 += 32) {
    // stage A (f32): 1024 16B-chunks, XOR-swizzled chunk position
#pragma unroll
    for (int it = 0; it < 4; ++it) {
      int slot = tid + it * 256;
      int row = slot >> 3, pos = slot & 7;
      int cc  = pos ^ (row & 7);
      async_copy16(A + (m0 + row) * K + k0 + cc * 4, &Ashf[slot * 4]);
    }
    // stage B (bf16): 512 chunks
#pragma unroll
    for (int it = 0; it < 2; ++it) {
      int slot = tid + it * 256;
      async_copy16(Bm + (n0 + (slot >> 2)) * K + k0 + (slot & 3) * 8, &Bsh[slot * 8]);
    }
    __syncthreads();

    bf16x8 af[4], bfr[4];
#pragma unroll
    for (int i = 0; i < 4; ++i) {
      int row = wr * 64 + i * 16 + l16;
      int p0 = (2 * quad) ^ (row & 7);
      f32x4 lo = *(const f32x4*)&Ashf[row * 32 + p0 * 4];
      f32x4 hi = *(const f32x4*)&Ashf[row * 32 + (p0 ^ 1) * 4];
      bf16x8 t;
      t[0] = (__bf16)lo[0]; t[1] = (__bf16)lo[1]; t[2] = (__bf16)lo[2]; t[3] = (__bf16)lo[3];
      t[4] = (__bf16)hi[0]; t[5] = (__bf16)hi[1]; t[6] = (__bf16)hi[2]; t[7] = (__bf16)hi[3];
      af[i] = t;
    }
#pragma unroll
    for (int j = 0; j < 4; ++j)
      bfr[j] = *(const bf16x8*)&Bsh[(wc * 64 + j * 16 + l16) * 32 + quad * 8];
#pragma unroll
    for (int i = 0; i < 4; ++i)
#pragma unroll
      for (int j = 0; j < 4; ++j)
        acc[i][j] = __builtin_amdgcn_mfma_f32_16x16x32_bf16(af[i], bfr[j], acc[i][j], 0, 0, 0);
    __syncthreads();
  }

#pragma unroll
  for (int i = 0; i < 4; ++i)
#pragma unroll
    for (int j = 0; j < 4; ++j)
#pragma unroll
      for (int r = 0; r < 4; ++r) {
        size_t row = m0 + wr * 64 + i * 16 + quad * 4 + r;
        size_t col = n0 + wc * 64 + j * 16 + l16;
        C[row * N + col] = (__bf16)acc[i][j][r];
      }
}

// ---------------- bf16 GEMM (out-proj): C[M,N] = A[M,K] @ B[N,K]^T ----------------
template <int BM, int BN, typename OutT>
__global__ __launch_bounds__(256, 2)
void gemm_bt(const __bf16* __restrict__ A, const __bf16* __restrict__ Bm,
             OutT* __restrict__ C, int M, int N, int K) {
  constexpr int MI = BM / 32, NJ = BN / 32;
  __shared__ __bf16 Ash[BM * 32];
  __shared__ __bf16 Bsh[BN * 32];

  const int tid  = threadIdx.x;
  const int lane = tid & 63;
  const int w    = tid >> 6;
  const int quad = lane >> 4;
  const int l16  = lane & 15;
  const int wr   = w >> 1, wc = w & 1;
  const size_t m0 = (size_t)blockIdx.x * BM;
  const size_t n0 = (size_t)blockIdx.y * BN;

  f32x4 acc[MI][NJ] = {};

  for (int k0 = 0; k0 < K; k0 += 32) {
#pragma unroll
    for (int it = 0; it < BM / 64; ++it) {
      int slot = tid + it * 256;
      async_copy16(A + (m0 + (slot >> 2)) * K + k0 + (slot & 3) * 8, &Ash[slot * 8]);
    }
#pragma unroll
    for (int it = 0; it < BN / 64; ++it) {
      int slot = tid + it * 256;
      async_copy16(Bm + (n0 + (slot >> 2)) * K + k0 + (slot & 3) * 8, &Bsh[slot * 8]);
    }
    __syncthreads();
    bf16x8 af[MI], bfr[NJ];
#pragma unroll
    for (int i = 0; i < MI; ++i)
      af[i] = *(const bf16x8*)&Ash[(wr * (BM / 2) + i * 16 + l16) * 32 + quad * 8];
#pragma unroll
    for (int j = 0; j < NJ; ++j)
      bfr[j] = *(const bf16x8*)&Bsh[(wc * (BN / 2) + j * 16 + l16) * 32 + quad * 8];
#pragma unroll
    for (int i = 0; i < MI; ++i)
#pragma unroll
      for (int j = 0; j < NJ; ++j)
        acc[i][j] = __builtin_amdgcn_mfma_f32_16x16x32_bf16(af[i], bfr[j], acc[i][j], 0, 0, 0);
    __syncthreads();
  }

#pragma unroll
  for (int i = 0; i < MI; ++i)
#pragma unroll
    for (int j = 0; j < NJ; ++j)
#pragma unroll
      for (int r = 0; r < 4; ++r) {
        size_t row = m0 + wr * (BM / 2) + i * 16 + quad * 4 + r;
        size_t col = n0 + wc * (BN / 2) + j * 16 + l16;
        C[row * N + col] = (OutT)acc[i][j][r];
      }
}

// ---------------- V transpose: Vp[B*S][D] -> Vt[B][D][S] ----------------
__global__ __launch_bounds__(256, 4)
void transpose_v(const __bf16* __restrict__ Vp, __bf16* __restrict__ Vt) {
  __shared__ __bf16 L[64 * 65];
  const int t  = threadIdx.x;
  const int s0 = blockIdx.x * 64, d0 = blockIdx.y * 64, b = blockIdx.z;
#pragma unroll
  for (int it = 0; it < 2; ++it) {
    int slot = t + it * 256;
    int sl = slot >> 3, c = slot & 7;
    int4 v = *(const int4*)&Vp[((size_t)(b * SEQ + s0 + sl)) * D_MODEL + d0 + c * 8];
    __bf16 tmp[8];
    *(int4*)tmp = v;
#pragma unroll
    for (int e = 0; e < 8; ++e) L[(c * 8 + e) * 65 + sl] = tmp[e];
  }
  __syncthreads();
#pragma unroll
  for (int it = 0; it < 2; ++it) {
    int slot = t + it * 256;
    int dl = slot >> 3, c2 = slot & 7;
    __bf16 tmp[8];
#pragma unroll
    for (int e = 0; e < 8; ++e) tmp[e] = L[dl * 65 + c2 * 8 + e];
    *(int4*)&Vt[((size_t)(b * D_MODEL + d0 + dl)) * SEQ + s0 + c2 * 8] = *(int4*)tmp;
  }
}

// ---------------- causal flash attention ----------------
// Singleton q-tiles: grid (bh=32 fastest, qt descending) = 1024 blocks ->
// 3 blocks/CU (r5 had 512 = 2/CU; occupancy was the binding constraint).
// Epilogue mt-loop fully unrolled (r4: runtime index spilled accumulators).
#define PS_W 40

__global__ __launch_bounds__(256, 3)
void attn_kernel(const __bf16* __restrict__ Qp, const __bf16* __restrict__ Kp,
                 const __bf16* __restrict__ Vt, __bf16* __restrict__ Xo) {
  __shared__ __bf16 Kb[2 * 2 * 64 * 32];     // [buf*2+dkhalf][key*32+dk]
  __shared__ __bf16 Vb[2 * 2 * 64 * 32];     // [buf*2+keyhalf][d*32+key]
  __shared__ __bf16 Ps[4 * 32 * PS_W];       // per-wave 32q x 32k
  __shared__ float  Xch[2 * 16 * 66];        // O exchange
  __shared__ float  Lsum[2 * 32];

  const int tid  = threadIdx.x;
  const int lane = tid & 63;
  const int w    = tid >> 6;
  const int qh   = w >> 1, kh = w & 1;
  const int quad = lane >> 4;
  const int l16  = lane & 15;
  const int bh   = blockIdx.x;               // fastest -> XCD spread
  const int qt   = 31 - blockIdx.y;          // longest blocks dispatch first
  const int b    = bh >> 4, h = bh & 15;
  const int q0   = qt * 64;
  const size_t baseRow = (size_t)b * SEQ;
  const int colBase = h * DK;

  const int srow = w * 16 + (lane >> 2);
  const int sk   = (lane & 3) * 8;

  const float c1 = 0.18033688011f;           // 0.125 * log2(e)
  const float c2 = -23.083120654f;           // constant softmax shift

  // Q fragments: rows q0 + qh*32 + mt*16 + l16, dk = kd*32 + quad*8
  bf16x8 aq[2][2];
  {
    const __bf16* qrow = Qp + (baseRow + q0 + qh * 32 + l16) * D_MODEL + colBase;
#pragma unroll
    for (int mt = 0; mt < 2; ++mt)
#pragma unroll
      for (int kd = 0; kd < 2; ++kd)
        aq[mt][kd] = *(const bf16x8*)(qrow + (size_t)mt * 16 * D_MODEL + kd * 32 + quad * 8);
  }

  f32x4 oacc[2][4] = {};
  float plsum[2][4] = {};

  {  // prologue: stage j=0 into buf 0
    const __bf16* kbase = Kp + (baseRow + srow) * D_MODEL + colBase + sk;
    async_copy16(kbase,      &Kb[0 * 2048 + srow * 32 + sk]);
    async_copy16(kbase + 32, &Kb[1 * 2048 + srow * 32 + sk]);
    const __bf16* vbase = Vt + ((size_t)b * D_MODEL + colBase + srow) * SEQ + sk;
    async_copy16(vbase,      &Vb[0 * 2048 + srow * 32 + sk]);
    async_copy16(vbase + 32, &Vb[1 * 2048 + srow * 32 + sk]);
  }

  for (int j = 0; j <= qt; ++j) {
    const int bf = j & 1;
    __syncthreads();   // buf[bf] staged; prior reads done

    if (j < qt) {
      const int nb = bf ^ 1;
      const __bf16* kbase = Kp + (baseRow + (size_t)(j + 1) * 64 + srow) * D_MODEL + colBase + sk;
      async_copy16(kbase,      &Kb[(nb * 2 + 0) * 2048 + srow * 32 + sk]);
      async_copy16(kbase + 32, &Kb[(nb * 2 + 1) * 2048 + srow * 32 + sk]);
      const __bf16* vbase = Vt + ((size_t)b * D_MODEL + colBase + srow) * SEQ + (size_t)(j + 1) * 64 + sk;
      async_copy16(vbase,      &Vb[(nb * 2 + 0) * 2048 + srow * 32 + sk]);
      async_copy16(vbase + 32, &Vb[(nb * 2 + 1) * 2048 + srow * 32 + sk]);
    }

    // S quadrant: 32 q x 32 keys
    f32x4 sacc[2][2] = {};
#pragma unroll
    for (int kd = 0; kd < 2; ++kd) {
      bf16x8 bk0 = *(const bf16x8*)&Kb[(bf * 2 + kd) * 2048 + (kh * 32 + l16) * 32 + quad * 8];
      bf16x8 bk1 = *(const bf16x8*)&Kb[(bf * 2 + kd) * 2048 + (kh * 32 + 16 + l16) * 32 + quad * 8];
      sacc[0][0] = __builtin_amdgcn_mfma_f32_16x16x32_bf16(aq[0][kd], bk0, sacc[0][0], 0, 0, 0);
      sacc[0][1] = __builtin_amdgcn_mfma_f32_16x16x32_bf16(aq[0][kd], bk1, sacc[0][1], 0, 0, 0);
      sacc[1][0] = __builtin_amdgcn_mfma_f32_16x16x32_bf16(aq[1][kd], bk0, sacc[1][0], 0, 0, 0);
      sacc[1][1] = __builtin_amdgcn_mfma_f32_16x16x32_bf16(aq[1][kd], bk1, sacc[1][1], 0, 0, 0);
    }

    // flat softmax + P to LDS (wave-private quadrant)
    const bool diag = (j == qt);
#pragma unroll
    for (int mt = 0; mt < 2; ++mt)
#pragma unroll
      for (int nt2 = 0; nt2 < 2; ++nt2)
#pragma unroll
        for (int r = 0; r < 4; ++r) {
          float arg = fmaf(sacc[mt][nt2][r], c1, c2);
          if (diag) {
            int rowg = q0 + qh * 32 + mt * 16 + quad * 4 + r;
            int colg = j * 64 + kh * 32 + nt2 * 16 + l16;
            if (colg > rowg) arg = -1e30f;
          }
          float p = __builtin_amdgcn_exp2f(arg);
          plsum[mt][r] += p;
          Ps[(w * 32 + mt * 16 + quad * 4 + r) * PS_W + nt2 * 16 + l16] = (__bf16)p;
        }

    // O += P V  (keys = wave's kh half)
    bf16x8 bv[4];
#pragma unroll
    for (int nt = 0; nt < 4; ++nt)
      bv[nt] = *(const bf16x8*)&Vb[(bf * 2 + kh) * 2048 + (nt * 16 + l16) * 32 + quad * 8];
#pragma unroll
    for (int mt = 0; mt < 2; ++mt) {
      bf16x8 ap = *(const bf16x8*)&Ps[(w * 32 + mt * 16 + l16) * PS_W + quad * 8];
#pragma unroll
      for (int nt = 0; nt < 4; ++nt)
        oacc[mt][nt] = __builtin_amdgcn_mfma_f32_16x16x32_bf16(ap, bv[nt], oacc[mt][nt], 0, 0, 0);
    }
  }

  // epilogue: reduce plsum over l16, exchange O + lsum across kh pair, store
  float lred[2][4];
#pragma unroll
  for (int mt = 0; mt < 2; ++mt)
#pragma unroll
    for (int r = 0; r < 4; ++r) {
      float l = plsum[mt][r];
      for (int off = 1; off < 16; off <<= 1) l += __shfl_xor(l, off, 64);
      lred[mt][r] = l;
    }

#pragma unroll
  for (int mt = 0; mt < 2; ++mt) {   // FULLY UNROLLED (r4 spill note)
    __syncthreads();
    if (kh == 1) {
#pragma unroll
      for (int nt = 0; nt < 4; ++nt)
#pragma unroll
        for (int r = 0; r < 4; ++r)
          Xch[(qh * 16 + quad * 4 + r) * 66 + nt * 16 + l16] = oacc[mt][nt][r];
#pragma unroll
      for (int r = 0; r < 4; ++r)
        Lsum[qh * 32 + mt * 16 + quad * 4 + r] = lred[mt][r];
    }
    __syncthreads();
    if (kh == 0) {
#pragma unroll
      for (int r = 0; r < 4; ++r) {
        float lt  = lred[mt][r] + Lsum[qh * 32 + mt * 16 + quad * 4 + r];
        float inv = 1.0f / lt;
        size_t row = baseRow + q0 + qh * 32 + mt * 16 + quad * 4 + r;
#pragma unroll
        for (int nt = 0; nt < 4; ++nt) {
          float o = oacc[mt][nt][r] + Xch[(qh * 16 + quad * 4 + r) * 66 + nt * 16 + l16];
          Xo[row * D_MODEL + colBase + nt * 16 + l16] = (__bf16)(o * inv);
        }
      }
    }
  }
}

// ---------------- launch ----------------
extern "C" void kernel_launch(void* const* d_in, const int* in_sizes, int n_in,
                              void* d_out, int out_size, void* d_ws, size_t ws_size,
                              hipStream_t stream) {
  const float* q  = (const float*)d_in[0];
  const float* k  = (const float*)d_in[1];
  const float* v  = (const float*)d_in[2];
  const float* wq = (const float*)d_in[3];
  const float* wk = (const float*)d_in[4];
  const float* wv = (const float*)d_in[5];
  const float* wo = (const float*)d_in[6];
  float* out = (float*)d_out;

  const size_t MD = (size_t)BATCH * SEQ * D_MODEL;
  const size_t WD = (size_t)D_MODEL * D_MODEL;
  __bf16* ws  = (__bf16*)d_ws;
  __bf16* Qp  = ws;
  __bf16* Kp  = Qp + MD;
  __bf16* Vp  = Kp + MD;
  __bf16* Xa  = Vp + MD;
  __bf16* Vt  = Xa + MD;
  __bf16* wqb = Vt + MD;
  __bf16* wkb = wqb + WD;
  __bf16* wvb = wkb + WD;
  __bf16* wob = wvb + WD;

  // weight casts only: 4 x 1Mi elems
  cast_w<<<dim3((int)(WD / 1024), 4), 256, 0, stream>>>(wq, wk, wv, wo, wqb, wkb, wvb, wob);

  // Q/K/V projections, A read in f32 directly
  gemm_af32_bt<<<dim3(32, 8, 3), 256, 0, stream>>>(
      q, k, v, wqb, wkb, wvb, Qp, Kp, Vp,
      BATCH * SEQ, D_MODEL, D_MODEL);

  // V -> V^T (per batch)
  transpose_v<<<dim3(SEQ / 64, D_MODEL / 64, BATCH), 256, 0, stream>>>(Vp, Vt);

  // causal attention: 1024 blocks (bh fastest, qt descending)
  attn_kernel<<<dim3(BATCH * NHEADS, 32), 256, 0, stream>>>(Qp, Kp, Vt, Xa);

  // output projection -> f32 out
  gemm_bt<64, 128, float><<<dim3(64, 8), 256, 0, stream>>>(
      Xa, wob, out, BATCH * SEQ, D_MODEL, D_MODEL);
}

// Round 8
// 200.383 us; speedup vs baseline: 1.1231x; 1.1231x over previous
//
#include <hip/hip_runtime.h>
#include <hip/hip_bf16.h>
#include <stdint.h>

#define D_MODEL 1024
#define NHEADS  16
#define DK      64
#define SEQ     2048
#define BATCH   2

typedef __bf16 bf16x8 __attribute__((ext_vector_type(8)));
typedef __bf16 bf16x4 __attribute__((ext_vector_type(4)));
typedef float  f32x4  __attribute__((ext_vector_type(4)));

__device__ __forceinline__ void async_copy16(const void* g, void* l) {
  __builtin_amdgcn_global_load_lds(
      (__attribute__((address_space(1))) void*)g,
      (__attribute__((address_space(3))) void*)l, 16, 0, 0);
}

// ---------------- fused casts: 3 x MD + 4 x WD arrays ----------------
__global__ void cast_all(const float* __restrict__ q, const float* __restrict__ k,
                         const float* __restrict__ v, const float* __restrict__ wq,
                         const float* __restrict__ wk, const float* __restrict__ wv,
                         const float* __restrict__ wo,
                         __bf16* __restrict__ oq, __bf16* __restrict__ ok,
                         __bf16* __restrict__ ov, __bf16* __restrict__ owq,
                         __bf16* __restrict__ owk, __bf16* __restrict__ owv,
                         __bf16* __restrict__ owo) {
  constexpr unsigned Q4 = (unsigned)(BATCH * SEQ * D_MODEL) / 4;  // 2^20
  constexpr unsigned W4 = (unsigned)(D_MODEL * D_MODEL) / 4;      // 2^18
  unsigned i = blockIdx.x * 256u + threadIdx.x;
  const float* in; __bf16* out; unsigned off;
  if (i < 3 * Q4) {
    unsigned z = i >> 20; off = i & (Q4 - 1);
    in  = z == 0 ? q : z == 1 ? k : v;
    out = z == 0 ? oq : z == 1 ? ok : ov;
  } else {
    unsigned j = i - 3 * Q4;
    unsigned z = j >> 18; off = j & (W4 - 1);
    in  = z == 0 ? wq : z == 1 ? wk : z == 2 ? wv : wo;
    out = z == 0 ? owq : z == 1 ? owk : z == 2 ? owv : owo;
  }
  float4 val = *(const float4*)(in + (size_t)off * 4);
  bf16x4 o;
  o.x = (__bf16)val.x; o.y = (__bf16)val.y; o.z = (__bf16)val.z; o.w = (__bf16)val.w;
  *(bf16x4*)(out + (size_t)off * 4) = o;
}

// ---------------- proj GEMM + fused V transpose ----------------
// z=0: Qp = qbf@Wq^T ; z=1: Kp = kbf@Wk^T ; z=2: Vt[b][d][s] = (vbf@Wv^T)^T
// 3 blocks/CU: 768 blocks all co-resident (no residency tail).
__global__ __launch_bounds__(256, 3)
void gemm_proj(const __bf16* __restrict__ A0, const __bf16* __restrict__ A1, const __bf16* __restrict__ A2,
               const __bf16* __restrict__ B0, const __bf16* __restrict__ B1, const __bf16* __restrict__ B2,
               __bf16* __restrict__ Qp, __bf16* __restrict__ Kp, __bf16* __restrict__ Vt) {
  constexpr int K = D_MODEL, N = D_MODEL;
  const int zi = blockIdx.z;
  const __bf16* A; const __bf16* Bm;
  if (zi == 0)      { A = A0; Bm = B0; }
  else if (zi == 1) { A = A1; Bm = B1; }
  else              { A = A2; Bm = B2; }

  __shared__ __bf16 Ash[128 * 32];
  __shared__ __bf16 Bsh[128 * 32];
  __shared__ __align__(16) __bf16 Tr[128 * 136];   // V-transpose staging (epilogue only)

  const int tid  = threadIdx.x;
  const int lane = tid & 63;
  const int w    = tid >> 6;
  const int quad = lane >> 4;
  const int l16  = lane & 15;
  const int wr   = w >> 1, wc = w & 1;
  const size_t m0 = (size_t)blockIdx.x * 128;   // M on x: same-A blocks share XCD
  const size_t n0 = (size_t)blockIdx.y * 128;

  f32x4 acc[4][4] = {};

  for (int k0 = 0; k0 < K; k0 += 32) {
#pragma unroll
    for (int it = 0; it < 2; ++it) {
      int slot = tid + it * 256;
      async_copy16(A + (m0 + (slot >> 2)) * K + k0 + (slot & 3) * 8, &Ash[slot * 8]);
    }
#pragma unroll
    for (int it = 0; it < 2; ++it) {
      int slot = tid + it * 256;
      async_copy16(Bm + (n0 + (slot >> 2)) * K + k0 + (slot & 3) * 8, &Bsh[slot * 8]);
    }
    __syncthreads();
    bf16x8 af[4], bfr[4];
#pragma unroll
    for (int i = 0; i < 4; ++i)
      af[i] = *(const bf16x8*)&Ash[(wr * 64 + i * 16 + l16) * 32 + quad * 8];
#pragma unroll
    for (int j = 0; j < 4; ++j)
      bfr[j] = *(const bf16x8*)&Bsh[(wc * 64 + j * 16 + l16) * 32 + quad * 8];
#pragma unroll
    for (int i = 0; i < 4; ++i)
#pragma unroll
      for (int j = 0; j < 4; ++j)
        acc[i][j] = __builtin_amdgcn_mfma_f32_16x16x32_bf16(af[i], bfr[j], acc[i][j], 0, 0, 0);
    __syncthreads();
  }

  if (zi != 2) {
    __bf16* C = (zi == 0) ? Qp : Kp;
#pragma unroll
    for (int i = 0; i < 4; ++i)
#pragma unroll
      for (int j = 0; j < 4; ++j)
#pragma unroll
        for (int r = 0; r < 4; ++r) {
          size_t row = m0 + wr * 64 + i * 16 + quad * 4 + r;
          size_t col = n0 + wc * 64 + j * 16 + l16;
          C[row * N + col] = (__bf16)acc[i][j][r];
        }
  } else {
    // transpose through LDS: Tr[d_local * 136 + s_local]
#pragma unroll
    for (int i = 0; i < 4; ++i)
#pragma unroll
      for (int j = 0; j < 4; ++j)
#pragma unroll
        for (int r = 0; r < 4; ++r)
          Tr[(wc * 64 + j * 16 + l16) * 136 + (wr * 64 + i * 16 + quad * 4 + r)] =
              (__bf16)acc[i][j][r];
    __syncthreads();
    const int b_  = (int)(m0 >> 11);        // m0 / SEQ  (tile never crosses batch)
    const int sl0 = (int)(m0 & 2047);
#pragma unroll
    for (int it = 0; it < 8; ++it) {
      int slot = tid + it * 256;
      int d = slot >> 4, sc = slot & 15;
      *(int4*)&Vt[((size_t)(b_ * D_MODEL) + n0 + d) * SEQ + sl0 + sc * 8] =
          *(const int4*)&Tr[d * 136 + sc * 8];
    }
  }
}

// ---------------- out-proj GEMM: out_f32[M,N] = Xa[M,K] @ Wo[N,K]^T ----------------
__global__ __launch_bounds__(256, 2)
void gemm_out(const __bf16* __restrict__ A, const __bf16* __restrict__ Bm,
              float* __restrict__ C) {
  constexpr int BM = 64, BN = 128, K = D_MODEL, N = D_MODEL;
  __shared__ __bf16 Ash[BM * 32];
  __shared__ __bf16 Bsh[BN * 32];

  const int tid  = threadIdx.x;
  const int lane = tid & 63;
  const int w    = tid >> 6;
  const int quad = lane >> 4;
  const int l16  = lane & 15;
  const int wr   = w >> 1, wc = w & 1;
  const size_t m0 = (size_t)blockIdx.x * BM;
  const size_t n0 = (size_t)blockIdx.y * BN;

  f32x4 acc[2][4] = {};

  for (int k0 = 0; k0 < K; k0 += 32) {
    {
      int slot = tid;
      async_copy16(A + (m0 + (slot >> 2)) * K + k0 + (slot & 3) * 8, &Ash[slot * 8]);
    }
#pragma unroll
    for (int it = 0; it < 2; ++it) {
      int slot = tid + it * 256;
      async_copy16(Bm + (n0 + (slot >> 2)) * K + k0 + (slot & 3) * 8, &Bsh[slot * 8]);
    }
    __syncthreads();
    bf16x8 af[2], bfr[4];
#pragma unroll
    for (int i = 0; i < 2; ++i)
      af[i] = *(const bf16x8*)&Ash[(wr * 32 + i * 16 + l16) * 32 + quad * 8];
#pragma unroll
    for (int j = 0; j < 4; ++j)
      bfr[j] = *(const bf16x8*)&Bsh[(wc * 64 + j * 16 + l16) * 32 + quad * 8];
#pragma unroll
    for (int i = 0; i < 2; ++i)
#pragma unroll
      for (int j = 0; j < 4; ++j)
        acc[i][j] = __builtin_amdgcn_mfma_f32_16x16x32_bf16(af[i], bfr[j], acc[i][j], 0, 0, 0);
    __syncthreads();
  }

#pragma unroll
  for (int i = 0; i < 2; ++i)
#pragma unroll
    for (int j = 0; j < 4; ++j)
#pragma unroll
      for (int r = 0; r < 4; ++r) {
        size_t row = m0 + wr * 32 + i * 16 + quad * 4 + r;
        size_t col = n0 + wc * 64 + j * 16 + l16;
        C[row * N + col] = acc[i][j][r];
      }
}

// ---------------- causal flash attention (r6 body: 1024 blocks, 3/CU) ----------------
#define PS_W 40

__global__ __launch_bounds__(256, 3)
void attn_kernel(const __bf16* __restrict__ Qp, const __bf16* __restrict__ Kp,
                 const __bf16* __restrict__ Vt, __bf16* __restrict__ Xo) {
  __shared__ __bf16 Kb[2 * 2 * 64 * 32];
  __shared__ __bf16 Vb[2 * 2 * 64 * 32];
  __shared__ __bf16 Ps[4 * 32 * PS_W];
  __shared__ float  Xch[2 * 16 * 66];
  __shared__ float  Lsum[2 * 32];

  const int tid  = threadIdx.x;
  const int lane = tid & 63;
  const int w    = tid >> 6;
  const int qh   = w >> 1, kh = w & 1;
  const int quad = lane >> 4;
  const int l16  = lane & 15;
  const int bh   = blockIdx.x;               // fastest -> XCD spread
  const int qt   = 31 - blockIdx.y;          // longest blocks dispatch first
  const int b    = bh >> 4, h = bh & 15;
  const int q0   = qt * 64;
  const size_t baseRow = (size_t)b * SEQ;
  const int colBase = h * DK;

  const int srow = w * 16 + (lane >> 2);
  const int sk   = (lane & 3) * 8;

  const float c1 = 0.18033688011f;           // 0.125 * log2(e)
  const float c2 = -23.083120654f;           // constant softmax shift

  bf16x8 aq[2][2];
  {
    const __bf16* qrow = Qp + (baseRow + q0 + qh * 32 + l16) * D_MODEL + colBase;
#pragma unroll
    for (int mt = 0; mt < 2; ++mt)
#pragma unroll
      for (int kd = 0; kd < 2; ++kd)
        aq[mt][kd] = *(const bf16x8*)(qrow + (size_t)mt * 16 * D_MODEL + kd * 32 + quad * 8);
  }

  f32x4 oacc[2][4] = {};
  float plsum[2][4] = {};

  {  // prologue: stage j=0 into buf 0
    const __bf16* kbase = Kp + (baseRow + srow) * D_MODEL + colBase + sk;
    async_copy16(kbase,      &Kb[0 * 2048 + srow * 32 + sk]);
    async_copy16(kbase + 32, &Kb[1 * 2048 + srow * 32 + sk]);
    const __bf16* vbase = Vt + ((size_t)b * D_MODEL + colBase + srow) * SEQ + sk;
    async_copy16(vbase,      &Vb[0 * 2048 + srow * 32 + sk]);
    async_copy16(vbase + 32, &Vb[1 * 2048 + srow * 32 + sk]);
  }

  for (int j = 0; j <= qt; ++j) {
    const int bf = j & 1;
    __syncthreads();

    if (j < qt) {
      const int nb = bf ^ 1;
      const __bf16* kbase = Kp + (baseRow + (size_t)(j + 1) * 64 + srow) * D_MODEL + colBase + sk;
      async_copy16(kbase,      &Kb[(nb * 2 + 0) * 2048 + srow * 32 + sk]);
      async_copy16(kbase + 32, &Kb[(nb * 2 + 1) * 2048 + srow * 32 + sk]);
      const __bf16* vbase = Vt + ((size_t)b * D_MODEL + colBase + srow) * SEQ + (size_t)(j + 1) * 64 + sk;
      async_copy16(vbase,      &Vb[(nb * 2 + 0) * 2048 + srow * 32 + sk]);
      async_copy16(vbase + 32, &Vb[(nb * 2 + 1) * 2048 + srow * 32 + sk]);
    }

    f32x4 sacc[2][2] = {};
#pragma unroll
    for (int kd = 0; kd < 2; ++kd) {
      bf16x8 bk0 = *(const bf16x8*)&Kb[(bf * 2 + kd) * 2048 + (kh * 32 + l16) * 32 + quad * 8];
      bf16x8 bk1 = *(const bf16x8*)&Kb[(bf * 2 + kd) * 2048 + (kh * 32 + 16 + l16) * 32 + quad * 8];
      sacc[0][0] = __builtin_amdgcn_mfma_f32_16x16x32_bf16(aq[0][kd], bk0, sacc[0][0], 0, 0, 0);
      sacc[0][1] = __builtin_amdgcn_mfma_f32_16x16x32_bf16(aq[0][kd], bk1, sacc[0][1], 0, 0, 0);
      sacc[1][0] = __builtin_amdgcn_mfma_f32_16x16x32_bf16(aq[1][kd], bk0, sacc[1][0], 0, 0, 0);
      sacc[1][1] = __builtin_amdgcn_mfma_f32_16x16x32_bf16(aq[1][kd], bk1, sacc[1][1], 0, 0, 0);
    }

    const bool diag = (j == qt);
#pragma unroll
    for (int mt = 0; mt < 2; ++mt)
#pragma unroll
      for (int nt2 = 0; nt2 < 2; ++nt2)
#pragma unroll
        for (int r = 0; r < 4; ++r) {
          float arg = fmaf(sacc[mt][nt2][r], c1, c2);
          if (diag) {
            int rowg = q0 + qh * 32 + mt * 16 + quad * 4 + r;
            int colg = j * 64 + kh * 32 + nt2 * 16 + l16;
            if (colg > rowg) arg = -1e30f;
          }
          float p = __builtin_amdgcn_exp2f(arg);
          plsum[mt][r] += p;
          Ps[(w * 32 + mt * 16 + quad * 4 + r) * PS_W + nt2 * 16 + l16] = (__bf16)p;
        }

    bf16x8 bv[4];
#pragma unroll
    for (int nt = 0; nt < 4; ++nt)
      bv[nt] = *(const bf16x8*)&Vb[(bf * 2 + kh) * 2048 + (nt * 16 + l16) * 32 + quad * 8];
#pragma unroll
    for (int mt = 0; mt < 2; ++mt) {
      bf16x8 ap = *(const bf16x8*)&Ps[(w * 32 + mt * 16 + l16) * PS_W + quad * 8];
#pragma unroll
      for (int nt = 0; nt < 4; ++nt)
        oacc[mt][nt] = __builtin_amdgcn_mfma_f32_16x16x32_bf16(ap, bv[nt], oacc[mt][nt], 0, 0, 0);
    }
  }

  float lred[2][4];
#pragma unroll
  for (int mt = 0; mt < 2; ++mt)
#pragma unroll
    for (int r = 0; r < 4; ++r) {
      float l = plsum[mt][r];
      for (int off = 1; off < 16; off <<= 1) l += __shfl_xor(l, off, 64);
      lred[mt][r] = l;
    }

#pragma unroll
  for (int mt = 0; mt < 2; ++mt) {   // FULLY UNROLLED (r4: runtime mt index spills accumulators)
    __syncthreads();
    if (kh == 1) {
#pragma unroll
      for (int nt = 0; nt < 4; ++nt)
#pragma unroll
        for (int r = 0; r < 4; ++r)
          Xch[(qh * 16 + quad * 4 + r) * 66 + nt * 16 + l16] = oacc[mt][nt][r];
#pragma unroll
      for (int r = 0; r < 4; ++r)
        Lsum[qh * 32 + mt * 16 + quad * 4 + r] = lred[mt][r];
    }
    __syncthreads();
    if (kh == 0) {
#pragma unroll
      for (int r = 0; r < 4; ++r) {
        float lt  = lred[mt][r] + Lsum[qh * 32 + mt * 16 + quad * 4 + r];
        float inv = 1.0f / lt;
        size_t row = baseRow + q0 + qh * 32 + mt * 16 + quad * 4 + r;
#pragma unroll
        for (int nt = 0; nt < 4; ++nt) {
          float o = oacc[mt][nt][r] + Xch[(qh * 16 + quad * 4 + r) * 66 + nt * 16 + l16];
          Xo[row * D_MODEL + colBase + nt * 16 + l16] = (__bf16)(o * inv);
        }
      }
    }
  }
}

// ---------------- launch ----------------
extern "C" void kernel_launch(void* const* d_in, const int* in_sizes, int n_in,
                              void* d_out, int out_size, void* d_ws, size_t ws_size,
                              hipStream_t stream) {
  const float* q  = (const float*)d_in[0];
  const float* k  = (const float*)d_in[1];
  const float* v  = (const float*)d_in[2];
  const float* wq = (const float*)d_in[3];
  const float* wk = (const float*)d_in[4];
  const float* wv = (const float*)d_in[5];
  const float* wo = (const float*)d_in[6];
  float* out = (float*)d_out;

  const size_t MD = (size_t)BATCH * SEQ * D_MODEL;
  const size_t WD = (size_t)D_MODEL * D_MODEL;
  __bf16* ws  = (__bf16*)d_ws;
  __bf16* Qp  = ws;
  __bf16* Kp  = Qp + MD;
  __bf16* Vt  = Kp + MD;
  __bf16* Xa  = Vt + MD;
  __bf16* qbf = Xa + MD;
  __bf16* kbf = qbf + MD;
  __bf16* vbf = kbf + MD;
  __bf16* wqb = vbf + MD;
  __bf16* wkb = wqb + WD;
  __bf16* wvb = wkb + WD;
  __bf16* wob = wvb + WD;

  // 1) casts: 3*MD/4 + 4*WD/4 = 4 Mi float4 -> 16384 blocks
  cast_all<<<16384, 256, 0, stream>>>(q, k, v, wq, wk, wv, wo,
                                      qbf, kbf, vbf, wqb, wkb, wvb, wob);

  // 2) Q/K/V projections (V written directly transposed)
  gemm_proj<<<dim3(32, 8, 3), 256, 0, stream>>>(
      qbf, kbf, vbf, wqb, wkb, wvb, Qp, Kp, Vt);

  // 3) causal attention: 1024 blocks (bh fastest, qt descending)
  attn_kernel<<<dim3(BATCH * NHEADS, 32), 256, 0, stream>>>(Qp, Kp, Vt, Xa);

  // 4) output projection -> f32 out
  gemm_out<<<dim3(64, 8), 256, 0, stream>>>(Xa, wob, out);
}